// Round 3
// baseline (171.621 us; speedup 1.0000x reference)
//
#include <hip/hip_runtime.h>
#include <hip/hip_fp16.h>

#define NEG  (-1e30f)
#define LN2F 0.69314718056f

// Problem dims (fixed by setup_inputs): B=16, TXT=128, MEL=512, NM=80
#define B_   16
#define TXT_ 128
#define MEL_ 512
#define NM_  80
#define IT_  8     // i-rows per lp block

#define CH_   80                  // mel rows per LDS chunk (5 x 16 groups)
#define NCH_  7                   // ceil(512/80); last chunk = 32 rows
#define CHD_  (CH_ * 64)          // dwords per chunk buffer = 5120 (20 KB)

typedef float vf2 __attribute__((ext_vector_type(2)));

// ---------------------------------------------------------------------------
// Kernel 1: log_prob_matrix (proven since R3). Also zeroes out[0].
// ---------------------------------------------------------------------------
__global__ __launch_bounds__(512) void lp_kernel(
    const float* __restrict__ mu_logvar,  // (B, TXT, 2*NM)
    const float* __restrict__ melspec,    // (B, NM, MEL)
    float* __restrict__ lp_out,           // (B, TXT, MEL)  = d_out + 1
    float* __restrict__ out0)             // d_out[0]
{
    const int i0 = blockIdx.x * IT_;
    const int b  = blockIdx.y;
    const int t  = threadIdx.x;

    __shared__ float2 s_wb[IT_][NM_];
    __shared__ float  s_cp[IT_ * NM_];
    __shared__ float  s_cc[IT_];

    for (int u = t; u < IT_ * NM_; u += 512) {   // 640 > 512: strided loop!
        int ii = u / NM_;
        int n  = u - ii * NM_;
        const float* row = mu_logvar + (size_t)(b * TXT_ + i0 + ii) * (2 * NM_);
        float mu = row[n];
        float lv = row[NM_ + n];
        float w  = __expf(-lv);
        s_wb[ii][n] = make_float2(w, -2.f * mu * w);
        s_cp[u]     = mu * mu * w + lv;
    }
    __syncthreads();
    if (t < IT_) {
        float c = 0.f;
        #pragma unroll
        for (int n = 0; n < NM_; ++n) c += s_cp[t * NM_ + n];
        s_cc[t] = c;
    }
    __syncthreads();

    const float* xcol = melspec + (size_t)b * NM_ * MEL_ + t;
    float acc[IT_];
    #pragma unroll
    for (int ii = 0; ii < IT_; ++ii) acc[ii] = 0.f;

    #pragma unroll 4
    for (int n = 0; n < NM_; ++n) {
        float x  = xcol[(size_t)n * MEL_];
        float x2 = x * x;
        #pragma unroll
        for (int ii = 0; ii < IT_; ++ii) {
            float2 wb = s_wb[ii][n];
            acc[ii] = fmaf(wb.x, x2, fmaf(wb.y, x, acc[ii]));
        }
    }

    const size_t rowbase = ((size_t)(b * TXT_ + i0)) * MEL_ + t;
    #pragma unroll
    for (int ii = 0; ii < IT_; ++ii) {
        lp_out[rowbase + (size_t)ii * MEL_] =
            (-0.5f / (float)NM_) * (acc[ii] + s_cc[ii]);
    }

    if (i0 == 0 && b == 0 && t == 0) *out0 = 0.f;
}

// ---------------------------------------------------------------------------
// Kernel 2 (fused wt + scan), STATIC shared only (<64 KB, no attribute call).
// One block per b, 512 threads. Thread t owns mel column t.
//
// Phase A (all): read own lp column (coalesced), f32 stash in 128 VGPRs,
//   mu_t = max + ln2; wave-reduce the musum contribution into wsum[8].
//   (f32 stash, NOT fp16: lp is O(100), fp16 ulp 0.06 would inject ~3%/step
//   error into w. Only w itself (<=1/2) is fp16-quantized: 2.4e-4 rel.)
// Write schedule: 3-buffer chunk pipeline, CH=80 rows (60 KB total).
//   pre-loop: chunks 0,1 -> buf0,buf1; iter c: wave0 scans chunk c from
//   buf[c%3] while threads of chunk c+2 write buf[(c+2)%3] (freed by scan
//   c-1, barrier-separated). One __syncthreads per iter; writes overlap scan.
// LDS swizzle D(row,p) = row*64 + (p ^ (row&31)): column-writes and the
//   scan's row-reads are both <=2-way (free).
// Phase C scan: proven R10 machinery — DPP shr1 + add/mul steps, exact
//   power-of-2 renorm every <=16 steps (CH=80=5x16 keeps groups aligned;
//   one 15-step prologue). fin latched at row==TendM1; rows past it are
//   valid data, harmless.
// ---------------------------------------------------------------------------
__device__ __forceinline__ float dpp_shr1_zero(float x) {
    int r = __builtin_amdgcn_update_dpp(
        0, __builtin_bit_cast(int, x), 0x138 /*wave_shr:1*/, 0xf, 0xf, false);
    return __builtin_bit_cast(float, r);
}

#define DPPMAX(M, CTRL, RM)                                               \
    do {                                                                  \
        int _t = __builtin_amdgcn_update_dpp(                             \
            __builtin_bit_cast(int, M), __builtin_bit_cast(int, M),       \
            CTRL, RM, 0xf, false);                                        \
        M = fmaxf(M, __builtin_bit_cast(float, _t));                      \
    } while (0)

__global__ __launch_bounds__(512) void fused_scan(
    const float* __restrict__ lp,          // (B, TXT, MEL) = d_out + 1
    const int* __restrict__ text_len, const int* __restrict__ mel_len,
    float* __restrict__ out0)
{
    __shared__ unsigned int wbuf[3 * CHD_];   // 60 KB
    __shared__ float wsum[8];
    __shared__ float s_lp00;

    const int b = blockIdx.x;
    const int t = threadIdx.x;                // mel column, 0..511
    const int l = t;                          // lane id when in wave 0
    const float* col = lp + (size_t)b * TXT_ * MEL_ + t;

    const int Tend = mel_len[b], TendM1 = Tend - 1;   // Tend in [256,512]

    // ---- Phase A: column read (f32 stash) + max ------------------------
    float vv[TXT_];
    float m = NEG;
    #pragma unroll
    for (int p = 0; p < TXT_; ++p) {
        float f = col[(size_t)p * MEL_];
        vv[p] = f;
        m = fmaxf(m, f);
    }
    const float mu_t = m + LN2F;

    float contrib = (t >= 1 && t <= TendM1) ? mu_t : 0.f;
    #pragma unroll
    for (int off = 32; off; off >>= 1) contrib += __shfl_down(contrib, off);
    if ((t & 63) == 0) wsum[t >> 6] = contrib;
    if (t == 0) s_lp00 = vv[0];               // lp[b][0][0]

    const int myc  = t / CH_;                 // this thread's chunk
    const int rloc = t - myc * CH_;
    unsigned int* wb = wbuf + (myc % 3) * CHD_ + rloc * 64;
    const int swz = t & 31;

    #define WRITEW()                                                      \
        do {                                                              \
            _Pragma("unroll")                                             \
            for (int p = 0; p < 64; ++p) {                                \
                float e0 = __expf(vv[2 * p]     - mu_t);                  \
                float e1 = __expf(vv[2 * p + 1] - mu_t);                  \
                wb[p ^ swz] = __builtin_bit_cast(                         \
                    unsigned int, __floats2half2_rn(e0, e1));             \
            }                                                             \
        } while (0)

    if (myc <= 1) WRITEW();                   // chunks 0,1 pre-filled
    __syncthreads();

    // ---- Phase C state -------------------------------------------------
    float s0 = (l == 0) ? 1.f : 0.f;
    float s1 = 0.f;
    float fin0 = 0.f, fin1 = 0.f;
    int   shift_acc = 0, fsh = 0;
    vf2 A[16], Bq[16];

    #define LOADN(ARR, RL0, N)                                            \
        _Pragma("unroll")                                                 \
        for (int j = 0; j < (N); ++j) {                                   \
            int rl = (RL0) + j;                                           \
            unsigned int u_ = bb[rl * 64 + (l ^ ((lo + rl) & 31))];       \
            float2 f_ = __half22float2(__builtin_bit_cast(__half2, u_));  \
            ARR[j].x = f_.x; ARR[j].y = f_.y;                             \
        }

    #define STEPN(ARR, RL0, N)                                            \
        _Pragma("unroll")                                                 \
        for (int j = 0; j < (N); ++j) {                                   \
            int row = lo + (RL0) + j;                                     \
            float nb  = dpp_shr1_zero(s1);                                \
            float ns0 = (s0 + nb) * ARR[j].x;                             \
            float ns1 = (s1 + s0) * ARR[j].y;                             \
            bool hit = (row == TendM1);                                   \
            fin0 = hit ? ns0 : fin0;                                      \
            fin1 = hit ? ns1 : fin1;                                      \
            fsh  = hit ? shift_acc : fsh;                                 \
            s0 = ns0; s1 = ns1;                                           \
        }

    #define RENORM16()                                                    \
        do {                                                              \
            float mm = fmaxf(s0, s1);                                     \
            DPPMAX(mm, 0x111, 0xf);   /* row_shr:1  */                    \
            DPPMAX(mm, 0x112, 0xf);   /* row_shr:2  */                    \
            DPPMAX(mm, 0x114, 0xf);   /* row_shr:4  */                    \
            DPPMAX(mm, 0x118, 0xf);   /* row_shr:8  */                    \
            DPPMAX(mm, 0x142, 0xa);   /* row_bcast:15 -> rows 1,3 */      \
            DPPMAX(mm, 0x143, 0xc);   /* row_bcast:31 -> rows 2,3 */      \
            float M = __builtin_bit_cast(                                 \
                float, __builtin_amdgcn_readlane(                         \
                           __builtin_bit_cast(int, mm), 63));             \
            if (M > 0.f) {                                                \
                int e;                                                    \
                (void)frexpf(M, &e);                                      \
                float sc = ldexpf(1.f, -e);                               \
                s0 *= sc; s1 *= sc;                                       \
                shift_acc += e;                                           \
            }                                                             \
        } while (0)

    for (int c = 0; c < NCH_; ++c) {
        if (t < 64) {
            const unsigned int* bb = wbuf + (c % 3) * CHD_;
            const int lo = c * CH_;
            if (c == 0) {
                LOADN(A, 1, 15); LOADN(Bq, 16, 16);
                STEPN(A, 1, 15);  RENORM16();
                LOADN(A, 32, 16); STEPN(Bq, 16, 16); RENORM16();
                LOADN(Bq, 48, 16); STEPN(A, 32, 16); RENORM16();
                LOADN(A, 64, 16); STEPN(Bq, 48, 16); RENORM16();
                STEPN(A, 64, 16); RENORM16();
            } else if (c < 6) {
                LOADN(A, 0, 16); LOADN(Bq, 16, 16);
                STEPN(A, 0, 16);  RENORM16();
                LOADN(A, 32, 16); STEPN(Bq, 16, 16); RENORM16();
                LOADN(Bq, 48, 16); STEPN(A, 32, 16); RENORM16();
                LOADN(A, 64, 16); STEPN(Bq, 48, 16); RENORM16();
                STEPN(A, 64, 16); RENORM16();
            } else {                          // c == 6: rows 480..511
                LOADN(A, 0, 16); LOADN(Bq, 16, 16);
                STEPN(A, 0, 16);  RENORM16();
                STEPN(Bq, 16, 16); RENORM16();
            }
        } else if (myc == c + 2) {
            WRITEW();                         // overlaps wave0's scan
        }
        __syncthreads();
    }
    #undef LOADN
    #undef STEPN
    #undef RENORM16
    #undef WRITEW

    if (t < 64) {
        int jstar = text_len[b] - 1;               // in [63,127]
        float vs = (jstar & 1) ? fin1 : fin0;
        int   vh = fsh;
        vs = __shfl(vs, jstar >> 1);
        vh = __shfl(vh, jstar >> 1);
        if (l == 0) {
            float ms = 0.f;
            #pragma unroll
            for (int k = 0; k < 8; ++k) ms += wsum[k];
            float val = __logf(vs) + (float)vh * LN2F + ms + s_lp00;
            atomicAdd(out0, -(val / (float)Tend) * (1.f / (float)B_));
        }
    }
}

// ---------------------------------------------------------------------------
extern "C" void kernel_launch(void* const* d_in, const int* in_sizes, int n_in,
                              void* d_out, int out_size, void* d_ws, size_t ws_size,
                              hipStream_t stream) {
    const float* mu_logvar = (const float*)d_in[0];
    const float* melspec   = (const float*)d_in[1];
    const int*   text_len  = (const int*)d_in[2];
    const int*   mel_len   = (const int*)d_in[3];

    float* out    = (float*)d_out;      // out[0] = mdn_loss, out[1..] = lp
    float* lp_out = out + 1;
    (void)d_ws; (void)ws_size;          // workspace no longer used

    dim3 g1(TXT_ / IT_, B_);
    lp_kernel<<<g1, MEL_, 0, stream>>>(mu_logvar, melspec, lp_out, out);
    fused_scan<<<B_, 512, 0, stream>>>(lp_out, text_len, mel_len, out);
}